// Round 3
// baseline (672.811 us; speedup 1.0000x reference)
//
#include <hip/hip_runtime.h>

#define SS 512
#define DD 768
#define TT 64

// ---------------------------------------------------------------------------
// Kernel 1: emissions GEMM  em[b*512+s][t] = sum_d x[b,s,d]*W[t,d] + bias[t]
// fp32 vector FMA, 128x64 tile, 256 threads, thread tile 8x4. (~24 us, OK)
// ---------------------------------------------------------------------------
__global__ __launch_bounds__(256) void emis_gemm(
    const float* __restrict__ X, const float* __restrict__ W,
    const float* __restrict__ bias, float* __restrict__ em)
{
    __shared__ __align__(16) float Xs[16][132];
    __shared__ __align__(16) float Ws[16][68];

    const int tid = threadIdx.x;
    const int m0  = blockIdx.x * 128;
    const int tm  = tid >> 4;
    const int tn  = tid & 15;
    const int lm  = tid >> 2;
    const int lkq = tid & 3;
    const int wt  = tid & 63;
    const int wkq = tid >> 6;

    float acc[8][4];
#pragma unroll
    for (int i = 0; i < 8; i++)
#pragma unroll
        for (int j = 0; j < 4; j++) acc[i][j] = 0.f;

    float4 xr0, xr1, wr;
    xr0 = *(const float4*)&X[(size_t)(m0 + lm) * DD + lkq * 4];
    xr1 = *(const float4*)&X[(size_t)(m0 + lm + 64) * DD + lkq * 4];
    wr  = *(const float4*)&W[(size_t)wt * DD + wkq * 4];

    for (int t = 0; t < 48; t++) {
        Xs[lkq * 4 + 0][lm] = xr0.x;  Xs[lkq * 4 + 1][lm] = xr0.y;
        Xs[lkq * 4 + 2][lm] = xr0.z;  Xs[lkq * 4 + 3][lm] = xr0.w;
        Xs[lkq * 4 + 0][lm + 64] = xr1.x;  Xs[lkq * 4 + 1][lm + 64] = xr1.y;
        Xs[lkq * 4 + 2][lm + 64] = xr1.z;  Xs[lkq * 4 + 3][lm + 64] = xr1.w;
        Ws[wkq * 4 + 0][wt] = wr.x;  Ws[wkq * 4 + 1][wt] = wr.y;
        Ws[wkq * 4 + 2][wt] = wr.z;  Ws[wkq * 4 + 3][wt] = wr.w;
        __syncthreads();

        if (t < 47) {
            const int k0 = (t + 1) * 16;
            xr0 = *(const float4*)&X[(size_t)(m0 + lm) * DD + k0 + lkq * 4];
            xr1 = *(const float4*)&X[(size_t)(m0 + lm + 64) * DD + k0 + lkq * 4];
            wr  = *(const float4*)&W[(size_t)wt * DD + k0 + wkq * 4];
        }

#pragma unroll
        for (int k = 0; k < 16; k++) {
            float a[8], bv[4];
            *(float4*)&a[0] = *(const float4*)&Xs[k][tm * 8];
            *(float4*)&a[4] = *(const float4*)&Xs[k][tm * 8 + 4];
            *(float4*)&bv[0] = *(const float4*)&Ws[k][tn * 4];
#pragma unroll
            for (int i = 0; i < 8; i++)
#pragma unroll
                for (int j = 0; j < 4; j++)
                    acc[i][j] = fmaf(a[i], bv[j], acc[i][j]);
        }
        __syncthreads();
    }

    const float4 bv4 = *(const float4*)&bias[tn * 4];
#pragma unroll
    for (int i = 0; i < 8; i++) {
        const size_t row = (size_t)(m0 + tm * 8 + i);
        float4 o;
        o.x = acc[i][0] + bv4.x;  o.y = acc[i][1] + bv4.y;
        o.z = acc[i][2] + bv4.z;  o.w = acc[i][3] + bv4.w;
        *(float4*)&em[row * TT + tn * 4] = o;
    }
}

// ---------------------------------------------------------------------------
// Kernel 2: Viterbi scan. ONE WAVE PER BATCH (64 blocks x 64 threads).
// lane = cur tag. No barriers, no inter-wave traffic in the step loop.
// Score exchange: 1 ds_write_b32 + 16 broadcast ds_read_b128 per step
// (all lanes read the same address -> conflict-free broadcast).
// Backpointers: packed 4 steps into u32, one coalesced global store / 4 steps.
// Emissions: 4-deep register prefetch ring (static regs via unroll-4).
// Candidate = (score[prev] + trans[prev][cur]) + em[cur]; tournament with
// left-wins ties == first-index argmax (matches reference exactly).
// ---------------------------------------------------------------------------
__global__ __launch_bounds__(64, 1) void viterbi(
    const float* __restrict__ em, const float* __restrict__ trans,
    unsigned int* __restrict__ hist32, int* __restrict__ bestTag)
{
    __shared__ __align__(16) float sc_lds[TT];

    const int b    = blockIdx.x;
    const int lane = threadIdx.x;
    const float* emb = em + (size_t)b * SS * TT;
    unsigned int* hb = hist32 + (size_t)b * 128 * TT;

    // transition column for this cur: trans[p][lane], p = 0..63
    float treg[TT];
#pragma unroll
    for (int p = 0; p < TT; p++) treg[p] = trans[p * TT + lane];

    // init: score = em[0]
    const float em0 = emb[lane];
    sc_lds[lane] = em0;
    float cur_score = em0;
    unsigned int packed = 0;

    // emission prefetch ring (steps s use em row s)
    float er0 = emb[1 * TT + lane];
    float er1 = emb[2 * TT + lane];
    float er2 = emb[3 * TT + lane];
    float er3 = emb[4 * TT + lane];

    auto step = [&](int s, float em_v) {
        const float4* sb = (const float4*)sc_lds;
        float v[TT];
#pragma unroll
        for (int i = 0; i < 16; i++) {
            const float4 s4 = sb[i];  // broadcast read
            v[4 * i + 0] = (s4.x + treg[4 * i + 0]) + em_v;
            v[4 * i + 1] = (s4.y + treg[4 * i + 1]) + em_v;
            v[4 * i + 2] = (s4.z + treg[4 * i + 2]) + em_v;
            v[4 * i + 3] = (s4.w + treg[4 * i + 3]) + em_v;
        }
        // tournament, left wins ties (== first-index argmax)
        float m1[32]; int a1[32];
#pragma unroll
        for (int i = 0; i < 32; i++) {
            const bool t = v[2 * i + 1] > v[2 * i];
            m1[i] = t ? v[2 * i + 1] : v[2 * i];
            a1[i] = 2 * i + (t ? 1 : 0);
        }
        float m2[16]; int a2[16];
#pragma unroll
        for (int i = 0; i < 16; i++) {
            const bool t = m1[2 * i + 1] > m1[2 * i];
            m2[i] = t ? m1[2 * i + 1] : m1[2 * i];
            a2[i] = t ? a1[2 * i + 1] : a1[2 * i];
        }
        float m3[8]; int a3[8];
#pragma unroll
        for (int i = 0; i < 8; i++) {
            const bool t = m2[2 * i + 1] > m2[2 * i];
            m3[i] = t ? m2[2 * i + 1] : m2[2 * i];
            a3[i] = t ? a2[2 * i + 1] : a2[2 * i];
        }
        float m4[4]; int a4[4];
#pragma unroll
        for (int i = 0; i < 4; i++) {
            const bool t = m3[2 * i + 1] > m3[2 * i];
            m4[i] = t ? m3[2 * i + 1] : m3[2 * i];
            a4[i] = t ? a3[2 * i + 1] : a3[2 * i];
        }
        float m5[2]; int a5[2];
#pragma unroll
        for (int i = 0; i < 2; i++) {
            const bool t = m4[2 * i + 1] > m4[2 * i];
            m5[i] = t ? m4[2 * i + 1] : m4[2 * i];
            a5[i] = t ? a4[2 * i + 1] : a4[2 * i];
        }
        const bool t6 = m5[1] > m5[0];
        const float best = t6 ? m5[1] : m5[0];
        const int   barg = t6 ? a5[1] : a5[0];

        cur_score = best;
        sc_lds[lane] = best;  // single wave: DS FIFO keeps order vs next reads
        packed |= (unsigned int)barg << ((s & 3) * 8);
        if ((s & 3) == 3) { hb[(s >> 2) * TT + lane] = packed; packed = 0u; }
    };

    // main loop: steps 1..508 unrolled by 4, prefetch 4 ahead
    for (int sb = 1; sb <= 505; sb += 4) {
        step(sb + 0, er0);  er0 = emb[(sb + 4) * TT + lane];
        step(sb + 1, er1);  er1 = emb[(sb + 5) * TT + lane];
        step(sb + 2, er2);  er2 = emb[(sb + 6) * TT + lane];
        step(sb + 3, er3);  er3 = emb[((sb + 7) <= 511 ? (sb + 7) : 511) * TT + lane];
    }
    // tail: steps 509, 510, 511
    step(509, er0);
    step(510, er1);
    step(511, er2);

    // final argmax across lanes (first-index ties)
    float fv = cur_score;
    int   fa = lane;
#pragma unroll
    for (int m = 1; m <= 32; m <<= 1) {
        const float vo = __shfl_xor(fv, m, 64);
        const int   ao = __shfl_xor(fa, m, 64);
        if (vo > fv || (vo == fv && ao < fa)) { fv = vo; fa = ao; }
    }
    if (lane == 0) bestTag[b] = fa;
}

// ---------------------------------------------------------------------------
// Kernel 3: backtrack via path doubling. 64 blocks x 256 threads.
// hist byte for (s,t) lives at ((s>>2)*64 + t)*4 + (s&3) within batch b.
// ---------------------------------------------------------------------------
__global__ __launch_bounds__(256) void backtrack(
    const unsigned int* __restrict__ hist32, const int* __restrict__ bestTag,
    unsigned char* __restrict__ tabA, unsigned char* __restrict__ tabB,
    int* __restrict__ out)
{
    const int b   = blockIdx.x;
    const int tid = threadIdx.x;
    const unsigned char* h8 = (const unsigned char*)(hist32 + (size_t)b * 128 * TT);
    unsigned char* A  = tabA + (size_t)b * SS * TT;
    unsigned char* Bt = tabB + (size_t)b * SS * TT;

    // G[s][t] = tag at s given tag at s+1 = t ; init from hist[s+1]
    for (int idx = tid; idx < 511 * 64; idx += 256) {
        const int s = (idx >> 6) + 1;
        const int t = idx & 63;
        A[idx] = h8[((s >> 2) * 64 + t) * 4 + (s & 3)];
    }
    __syncthreads();

    unsigned char* curT = A;
    unsigned char* nxtT = Bt;
    for (int d = 1; d < 511; d <<= 1) {
        for (int idx = tid; idx < 511 * 64; idx += 256) {
            const int s = idx >> 6;
            const int t = idx & 63;
            unsigned char r;
            if (s + d >= 511) {
                r = curT[idx];
            } else {
                const unsigned char mid = curT[(s + d) * 64 + t];
                r = curT[s * 64 + mid];
            }
            nxtT[idx] = r;
        }
        __syncthreads();
        unsigned char* tmp = curT; curT = nxtT; nxtT = tmp;
    }

    const int bt = bestTag[b];
    for (int s = tid; s < SS; s += 256) {
        const int tag = (s == 511) ? bt : (int)curT[(size_t)s * 64 + bt];
        out[(size_t)b * SS + s] = tag;
    }
}

// ---------------------------------------------------------------------------
extern "C" void kernel_launch(void* const* d_in, const int* in_sizes, int n_in,
                              void* d_out, int out_size, void* d_ws, size_t ws_size,
                              hipStream_t stream)
{
    const float* X     = (const float*)d_in[0];  // [64,512,768]
    const float* W     = (const float*)d_in[1];  // [64,768]
    const float* bias  = (const float*)d_in[2];  // [64]
    const float* trans = (const float*)d_in[3];  // [64,64]
    int* out = (int*)d_out;                      // [64,512] int32

    char* ws = (char*)d_ws;
    float*        em      = (float*)ws;                         // 8,388,608 B
    unsigned int* hist32  = (unsigned int*)(ws + 8388608);      // 2,097,152 B
    int*          bestTag = (int*)(ws + 10485760);              // 256 B
    unsigned char* tabA   = (unsigned char*)(ws + 10489856);    // 2,097,152 B
    unsigned char* tabB   = (unsigned char*)(ws + 12587008);    // 2,097,152 B

    emis_gemm<<<dim3(256), dim3(256), 0, stream>>>(X, W, bias, em);
    viterbi<<<dim3(64), dim3(64), 0, stream>>>(em, trans, hist32, bestTag);
    backtrack<<<dim3(64), dim3(256), 0, stream>>>(hist32, bestTag, tabA, tabB, out);
}